// Round 12
// baseline (483.083 us; speedup 1.0000x reference)
//
#include <hip/hip_runtime.h>
#include <hip/hip_bf16.h>
#include <stdint.h>

// MultiHeadedSelfAttention: B=2, L=4096, D=1024, H=1. fp32 inputs, FP32 output.
// Round 24 (= round-23 resubmit; prior bench was an infra failure, kernel
// never ran). Softmax round-trip eliminated: softmax_rows (134MB r/w) ->
// rowstat_rows (67MB read, 64KB write of per-row (max, 1/sumexp)). PV is
// pv_bt: proven gemm_bt body + in-register exp(v-m) on A(=S) fragments after
// ds_read + 1/s scaling in the fp32 epilogue. Same math as softmax->PV.
// NOTE: SQ_LDS_BANK_CONFLICT reads exactly 2^23 in every GEMM dispatch all
// session — broken counter on gfx950, ignored.
// Pipeline:
//   0. cast x (grid 4096); cast W4 (grid 2048)
//   1. QKp = x @ [Wq;Wk]^T    (8192x2048, K=1024)  grid 1024  [gemm_bt<1>]
//   2. Vt  = Wv @ x^T          (1024x8192)          grid 512   [gemm_bt<0>]
//   3. S_z = Q_z @ Kp_z^T/32   (2x 4096x4096)       grid 512   [gemm256_8ph]
//   4. rowstat: minv[row] = (m, 1/sum exp(S-m))     grid 8192
//   5. O_z = exp(S_z-m)/s @ V_z -> O (QKp region)   grid 512   [pv_bt]
//   6. out = O @ Wo^T -> FP32 d_out                 grid 512   [gemm_bt<1>]
// minv lives in xb's region (xb dead after Vt). ws layout otherwise as before.

typedef unsigned short u16;
typedef short short8 __attribute__((ext_vector_type(8)));
typedef float f32x4 __attribute__((ext_vector_type(4)));

__device__ __forceinline__ void async_ld16(void* lds, const void* g) {
  __builtin_amdgcn_global_load_lds(
      (const __attribute__((address_space(1))) unsigned int*)g,
      (__attribute__((address_space(3))) unsigned int*)lds,
      16, 0, 0);
}

__device__ __forceinline__ u16 f2bf(float f) {  // RNE
  unsigned u = __float_as_uint(f);
  u += 0x7FFFu + ((u >> 16) & 1u);
  return (u16)(u >> 16);
}

// fp32 -> bf16, 8 elems/thread. n must be a multiple of 8 (true here).
__global__ __launch_bounds__(256)
void cast_f32_bf16(const float* __restrict__ in, u16* __restrict__ out, int n) {
  const int i = (blockIdx.x * 256 + threadIdx.x) * 8;
  if (i >= n) return;
  float4 a = ((const float4*)(in + i))[0];
  float4 b = ((const float4*)(in + i))[1];
  uint4 o;
  o.x = (unsigned)f2bf(a.x) | ((unsigned)f2bf(a.y) << 16);
  o.y = (unsigned)f2bf(a.z) | ((unsigned)f2bf(a.w) << 16);
  o.z = (unsigned)f2bf(b.x) | ((unsigned)f2bf(b.y) << 16);
  o.w = (unsigned)f2bf(b.z) | ((unsigned)f2bf(b.w) << 16);
  *(uint4*)(out + i) = o;
}

// 4 weight matrices (each n = 1<<20 fp32) -> one contiguous bf16 region.
__global__ __launch_bounds__(256)
void cast_w4_bf16(const float* __restrict__ w0, const float* __restrict__ w1,
                  const float* __restrict__ w2, const float* __restrict__ w3,
                  u16* __restrict__ out) {
  const int idx = (blockIdx.x * 256 + threadIdx.x) * 8;
  const int which = idx >> 20;
  const int off = idx & 1048575;
  const float* src = which == 0 ? w0 : which == 1 ? w1 : which == 2 ? w2 : w3;
  float4 a = ((const float4*)(src + off))[0];
  float4 b = ((const float4*)(src + off))[1];
  uint4 o;
  o.x = (unsigned)f2bf(a.x) | ((unsigned)f2bf(a.y) << 16);
  o.y = (unsigned)f2bf(a.z) | ((unsigned)f2bf(a.w) << 16);
  o.z = (unsigned)f2bf(b.x) | ((unsigned)f2bf(b.y) << 16);
  o.w = (unsigned)f2bf(b.z) | ((unsigned)f2bf(b.w) << 16);
  *(uint4*)(out + idx) = o;
}

#define BM 128
#define BN 128
#define BK 32

// ---- 128^2 workhorse: triple-buffered, depth-3, counted vmcnt(8/4/0).
template <int XSWZ>
__global__ __launch_bounds__(256)
void gemm_bt(const u16* __restrict__ A, const u16* __restrict__ Bt,
             void* __restrict__ Cv, int K, int lda, int ldb, int ldc,
             long long sAz, long long sBz, long long sCz,
             float scale, int store_f32) {
  __shared__ u16 As[3][BM * BK];
  __shared__ u16 Bs[3][BN * BK];

  int bx, by, bz;
  if constexpr (XSWZ) {
    const int gx = gridDim.x, gy = gridDim.y;
    const int nwg = gx * gy * gridDim.z;
    const int lin = (blockIdx.z * gy + blockIdx.y) * gx + blockIdx.x;
    const int chunk = nwg >> 3;
    const int swz = (lin & 7) * chunk + (lin >> 3);
    bx = swz % gx;
    const int t1 = swz / gx;
    by = t1 % gy;
    bz = t1 / gy;
  } else {
    bx = blockIdx.x; by = blockIdx.y; bz = blockIdx.z;
  }

  A  += (long long)bz * sAz;
  Bt += (long long)bz * sBz;

  const int tid  = threadIdx.x;
  const int wave = tid >> 6;
  const int lane = tid & 63;
  const int wm   = wave >> 1;
  const int wn   = wave & 1;
  const int r15  = lane & 15;
  const int q4   = lane >> 4;

  const int tileM = by * BM;
  const int tileN = bx * BN;

  const int srow = tid >> 2;
  const int scol = ((tid & 3) ^ (srow & 3)) * 8;

  const u16* Aptr = A + (long long)tileM * lda + scol;
  const u16* Bptr = Bt + (long long)tileN * ldb + scol;

  auto stage = [&](int kt) {
    const int b = kt % 3;
    const int k0 = kt * BK;
    u16* as = &As[b][tid * 8];
    u16* bs = &Bs[b][tid * 8];
    async_ld16(as,        Aptr + (long long)srow * lda + k0);
    async_ld16(as + 2048, Aptr + (long long)(srow + 64) * lda + k0);
    async_ld16(bs,        Bptr + (long long)srow * ldb + k0);
    async_ld16(bs + 2048, Bptr + (long long)(srow + 64) * ldb + k0);
  };

  f32x4 zero = {0.f, 0.f, 0.f, 0.f};
  f32x4 acc[4][4];
#pragma unroll
  for (int i = 0; i < 4; ++i)
#pragma unroll
    for (int j = 0; j < 4; ++j) acc[i][j] = zero;

  const int csw = ((q4 ^ (r15 & 3)) * 8);

  const int NT = K / BK;
  stage(0);
  if (NT > 1) stage(1);
  if (NT > 2) stage(2);

  for (int kt = 0; kt < NT; ++kt) {
    const int rem = NT - 1 - kt;
    if (rem >= 2)      asm volatile("s_waitcnt vmcnt(8)" ::: "memory");
    else if (rem == 1) asm volatile("s_waitcnt vmcnt(4)" ::: "memory");
    else               asm volatile("s_waitcnt vmcnt(0)" ::: "memory");
    __builtin_amdgcn_s_barrier();

    const int b = kt % 3;
    const u16* as = &As[b][0];
    const u16* bs = &Bs[b][0];

    short8 af[4], bf[4];
#pragma unroll
    for (int i = 0; i < 4; ++i)
      af[i] = *(const short8*)&as[(wm * 64 + i * 16 + r15) * BK + csw];
#pragma unroll
    for (int i = 0; i < 4; ++i)
      bf[i] = *(const short8*)&bs[(wn * 64 + i * 16 + r15) * BK + csw];

    __builtin_amdgcn_s_setprio(1);
#pragma unroll
    for (int i = 0; i < 4; ++i)
#pragma unroll
      for (int j = 0; j < 4; ++j)
        acc[i][j] = __builtin_amdgcn_mfma_f32_16x16x32_bf16(af[i], bf[j], acc[i][j], 0, 0, 0);
    __builtin_amdgcn_s_setprio(0);

    __builtin_amdgcn_s_barrier();
    if (kt + 3 < NT) stage(kt + 3);
  }

#pragma unroll
  for (int i = 0; i < 4; ++i) {
#pragma unroll
    for (int j = 0; j < 4; ++j) {
      const int col = tileN + wn * 64 + j * 16 + r15;
#pragma unroll
      for (int r = 0; r < 4; ++r) {
        const int row = tileM + wm * 64 + i * 16 + q4 * 4 + r;
        const long long idx = (long long)bz * sCz + (long long)row * ldc + col;
        const float val = acc[i][j][r] * scale;
        if (store_f32) ((float*)Cv)[idx] = val;
        else           ((u16*)Cv)[idx] = f2bf(val);
      }
    }
  }
}

// ---- PV with fused softmax: A = raw scores S (bf16); af fragments are
// transformed in-register to exp(v - m_row) after ds_read; epilogue scales
// by 1/s_row in fp32. minv[row] = (m, 1/s) from rowstat_rows. Structure
// otherwise identical to gemm_bt<1> (XCD swizzle, depth-3, vmcnt(8/4/0)).
__global__ __launch_bounds__(256)
void pv_bt(const u16* __restrict__ A, const u16* __restrict__ Bt,
           u16* __restrict__ C, const float2* __restrict__ minv,
           int K, int lda, int ldb, int ldc,
           long long sAz, long long sBz, long long sCz) {
  __shared__ u16 As[3][BM * BK];
  __shared__ u16 Bs[3][BN * BK];

  const int gx = gridDim.x, gy = gridDim.y;
  const int nwg = gx * gy * gridDim.z;
  const int lin = (blockIdx.z * gy + blockIdx.y) * gx + blockIdx.x;
  const int chunk = nwg >> 3;
  const int swz = (lin & 7) * chunk + (lin >> 3);
  const int bx = swz % gx;
  const int t1 = swz / gx;
  const int by = t1 % gy;
  const int bz = t1 / gy;

  A  += (long long)bz * sAz;
  Bt += (long long)bz * sBz;

  const int tid  = threadIdx.x;
  const int wave = tid >> 6;
  const int lane = tid & 63;
  const int wm   = wave >> 1;
  const int wn   = wave & 1;
  const int r15  = lane & 15;
  const int q4   = lane >> 4;

  const int tileM = by * BM;
  const int tileN = bx * BN;

  const int srow = tid >> 2;
  const int scol = ((tid & 3) ^ (srow & 3)) * 8;

  const u16* Aptr = A + (long long)tileM * lda + scol;
  const u16* Bptr = Bt + (long long)tileN * ldb + scol;

  auto stage = [&](int kt) {
    const int b = kt % 3;
    const int k0 = kt * BK;
    u16* as = &As[b][tid * 8];
    u16* bs = &Bs[b][tid * 8];
    async_ld16(as,        Aptr + (long long)srow * lda + k0);
    async_ld16(as + 2048, Aptr + (long long)(srow + 64) * lda + k0);
    async_ld16(bs,        Bptr + (long long)srow * ldb + k0);
    async_ld16(bs + 2048, Bptr + (long long)(srow + 64) * ldb + k0);
  };

  // per-lane row maxima for the 4 af fragment rows (fixed across K loop)
  const int rbase = bz * 4096 + tileM + wm * 64 + r15;
  float am[4];
#pragma unroll
  for (int i = 0; i < 4; ++i) am[i] = minv[rbase + i * 16].x;

  // exp-transform one bf16x8 fragment: out = bf16(exp(v - m))
  auto xf = [&](short8 v, float m) -> short8 {
    union { short8 s; uint4 u; } in, out;
    in.s = v;
    unsigned w0 = in.u.x, w1 = in.u.y, w2 = in.u.z, w3 = in.u.w;
    unsigned o0, o1, o2, o3;
    {
      float lo = __uint_as_float(w0 << 16), hi = __uint_as_float(w0 & 0xFFFF0000u);
      o0 = (unsigned)f2bf(__expf(lo - m)) | ((unsigned)f2bf(__expf(hi - m)) << 16);
    }
    {
      float lo = __uint_as_float(w1 << 16), hi = __uint_as_float(w1 & 0xFFFF0000u);
      o1 = (unsigned)f2bf(__expf(lo - m)) | ((unsigned)f2bf(__expf(hi - m)) << 16);
    }
    {
      float lo = __uint_as_float(w2 << 16), hi = __uint_as_float(w2 & 0xFFFF0000u);
      o2 = (unsigned)f2bf(__expf(lo - m)) | ((unsigned)f2bf(__expf(hi - m)) << 16);
    }
    {
      float lo = __uint_as_float(w3 << 16), hi = __uint_as_float(w3 & 0xFFFF0000u);
      o3 = (unsigned)f2bf(__expf(lo - m)) | ((unsigned)f2bf(__expf(hi - m)) << 16);
    }
    out.u = make_uint4(o0, o1, o2, o3);
    return out.s;
  };

  f32x4 zero = {0.f, 0.f, 0.f, 0.f};
  f32x4 acc[4][4];
#pragma unroll
  for (int i = 0; i < 4; ++i)
#pragma unroll
    for (int j = 0; j < 4; ++j) acc[i][j] = zero;

  const int csw = ((q4 ^ (r15 & 3)) * 8);

  const int NT = K / BK;
  stage(0);
  if (NT > 1) stage(1);
  if (NT > 2) stage(2);

  for (int kt = 0; kt < NT; ++kt) {
    const int rem = NT - 1 - kt;
    if (rem >= 2)      asm volatile("s_waitcnt vmcnt(8)" ::: "memory");
    else if (rem == 1) asm volatile("s_waitcnt vmcnt(4)" ::: "memory");
    else               asm volatile("s_waitcnt vmcnt(0)" ::: "memory");
    __builtin_amdgcn_s_barrier();

    const int b = kt % 3;
    const u16* as = &As[b][0];
    const u16* bs = &Bs[b][0];

    short8 af[4], bf[4];
#pragma unroll
    for (int i = 0; i < 4; ++i)
      af[i] = *(const short8*)&as[(wm * 64 + i * 16 + r15) * BK + csw];
#pragma unroll
    for (int i = 0; i < 4; ++i)
      bf[i] = *(const short8*)&bs[(wn * 64 + i * 16 + r15) * BK + csw];

    // fused softmax numerator: af = exp(af - m_row)
#pragma unroll
    for (int i = 0; i < 4; ++i) af[i] = xf(af[i], am[i]);

    __builtin_amdgcn_s_setprio(1);
#pragma unroll
    for (int i = 0; i < 4; ++i)
#pragma unroll
      for (int j = 0; j < 4; ++j)
        acc[i][j] = __builtin_amdgcn_mfma_f32_16x16x32_bf16(af[i], bf[j], acc[i][j], 0, 0, 0);
    __builtin_amdgcn_s_setprio(0);

    __builtin_amdgcn_s_barrier();
    if (kt + 3 < NT) stage(kt + 3);
  }

  // epilogue: scale by 1/s_row (fp32), store bf16.
#pragma unroll
  for (int i = 0; i < 4; ++i) {
#pragma unroll
    for (int j = 0; j < 4; ++j) {
      const int col = tileN + wn * 64 + j * 16 + r15;
#pragma unroll
      for (int r = 0; r < 4; ++r) {
        const int row = tileM + wm * 64 + i * 16 + q4 * 4 + r;
        const float invs = minv[bz * 4096 + row].y;
        const long long idx = (long long)bz * sCz + (long long)row * ldc + col;
        C[idx] = f2bf(acc[i][j][r] * invs);
      }
    }
  }
}

// ---------------------------------------------------------------------------
// 256x256 fine-phase GEMM (scores) — unchanged from round 10.
// ---------------------------------------------------------------------------
__global__ __launch_bounds__(512, 2)
void gemm256_8ph(const u16* __restrict__ A, const u16* __restrict__ Bt,
                 u16* __restrict__ C, int K, int lda, int ldb, int ldc,
                 long long sAz, long long sBz, long long sCz, float scale) {
  __shared__ u16 smem[49152];  // 3 x (A 256x32 + B 256x32) u16 = 96 KiB

  const int gx = gridDim.x, gy = gridDim.y;
  const int nwg = gx * gy * gridDim.z;
  const int lin = (blockIdx.z * gy + blockIdx.y) * gx + blockIdx.x;
  const int chunk = nwg >> 3;
  const int swz = (lin & 7) * chunk + (lin >> 3);
  const int bx = swz % gx;
  const int t1 = swz / gx;
  const int by = t1 % gy;
  const int bz = t1 / gy;

  A  += (long long)bz * sAz;
  Bt += (long long)bz * sBz;
  const long long cbase = (long long)bz * sCz;

  const int tid  = threadIdx.x;
  const int wid  = tid >> 6;
  const int lane = tid & 63;
  const int wm   = wid >> 2;
  const int wn   = wid & 3;
  const int r15  = lane & 15;
  const int q4   = lane >> 4;

  const int tileM = by * 256;
  const int tileN = bx * 256;

  const int sr  = tid >> 2;
  const int gc8 = ((((tid & 3) - ((tid >> 3) & 3)) & 3)) * 8;

  const u16* Asrc = A  + (long long)(tileM + sr) * lda + gc8;
  const u16* Bsrc = Bt + (long long)(tileN + sr) * ldb + gc8;

  auto stage2A = [&](int kt) {
    u16* d = &smem[(kt % 3) * 16384 + tid * 8];
    async_ld16(d,        Asrc + kt * 32);
    async_ld16(d + 4096, Asrc + (long long)128 * lda + kt * 32);
  };
  auto stage2B = [&](int kt) {
    u16* d = &smem[(kt % 3) * 16384 + 8192 + tid * 8];
    async_ld16(d,        Bsrc + kt * 32);
    async_ld16(d + 4096, Bsrc + (long long)128 * ldb + kt * 32);
  };

  const int csw = (((q4 + (r15 >> 1)) & 3)) * 8;

  f32x4 acc[8][4];
#pragma unroll
  for (int i = 0; i < 8; ++i)
#pragma unroll
    for (int j = 0; j < 4; ++j) acc[i][j] = (f32x4){0.f, 0.f, 0.f, 0.f};

  const int NT = K >> 5;

  stage2A(0); stage2B(0);
  if (NT > 1) { stage2A(1); stage2B(1); }

  for (int t = 0; t < NT; ++t) {
    if (t + 1 < NT) asm volatile("s_waitcnt vmcnt(4)" ::: "memory");
    else            asm volatile("s_waitcnt vmcnt(0)" ::: "memory");
    __builtin_amdgcn_s_barrier();

    const u16* bufA = &smem[(t % 3) * 16384];
    const u16* bufB = bufA + 8192;

    short8 bf[4], af[4];
#pragma unroll
    for (int j = 0; j < 4; ++j)
      bf[j] = *(const short8*)&bufB[(wn * 64 + j * 16 + r15) * 32 + csw];
#pragma unroll
    for (int i = 0; i < 4; ++i)
      af[i] = *(const short8*)&bufA[(wm * 128 + i * 16 + r15) * 32 + csw];
    if (t + 2 < NT) stage2A(t + 2);
    __builtin_amdgcn_s_barrier();

    __builtin_amdgcn_s_setprio(1);
#pragma unroll
    for (int i = 0; i < 4; ++i)
#pragma unroll
      for (int j = 0; j < 4; ++j)
        acc[i][j] = __builtin_amdgcn_mfma_f32_16x16x32_bf16(af[i], bf[j], acc[i][j], 0, 0, 0);
    __builtin_amdgcn_s_setprio(0);
    __builtin_amdgcn_s_barrier();

#pragma unroll
    for (int i = 0; i < 4; ++i)
      af[i] = *(const short8*)&bufA[(wm * 128 + 64 + i * 16 + r15) * 32 + csw];
    if (t + 2 < NT) stage2B(t + 2);
    __builtin_amdgcn_s_barrier();

    __builtin_amdgcn_s_setprio(1);
#pragma unroll
    for (int i = 0; i < 4; ++i)
#pragma unroll
      for (int j = 0; j < 4; ++j)
        acc[4 + i][j] = __builtin_amdgcn_mfma_f32_16x16x32_bf16(af[i], bf[j], acc[4 + i][j], 0, 0, 0);
    __builtin_amdgcn_s_setprio(0);
    __builtin_amdgcn_s_barrier();
  }

  const int crow = tileM + wm * 128 + q4 * 4;
  const int ccol = tileN + wn * 64 + r15;
#pragma unroll
  for (int mi = 0; mi < 8; ++mi)
#pragma unroll
    for (int nj = 0; nj < 4; ++nj)
#pragma unroll
      for (int r = 0; r < 4; ++r) {
        const long long row = crow + mi * 16 + r;
        C[cbase + row * ldc + (ccol + nj * 16)] = f2bf(acc[mi][nj][r] * scale);
      }
}

// Per-row (max, 1/sum exp) over 4096 bf16 columns. grid = rows, block = 256.
__global__ __launch_bounds__(256)
void rowstat_rows(const u16* __restrict__ S, float2* __restrict__ minv) {
  const int tid = threadIdx.x;
  const u16* rp = S + (long long)blockIdx.x * 4096;

  uint4 a = ((const uint4*)rp)[tid * 2];
  uint4 b = ((const uint4*)rp)[tid * 2 + 1];
  unsigned w[8] = {a.x, a.y, a.z, a.w, b.x, b.y, b.z, b.w};
  float v[16];
#pragma unroll
  for (int i = 0; i < 8; ++i) {
    v[2 * i]     = __uint_as_float(w[i] << 16);
    v[2 * i + 1] = __uint_as_float(w[i] & 0xFFFF0000u);
  }

  float m = v[0];
#pragma unroll
  for (int i = 1; i < 16; ++i) m = fmaxf(m, v[i]);
#pragma unroll
  for (int o = 32; o > 0; o >>= 1) m = fmaxf(m, __shfl_xor(m, o));
  __shared__ float redm[4];
  __shared__ float reds[4];
  const int wave = tid >> 6;
  if ((tid & 63) == 0) redm[wave] = m;
  __syncthreads();
  m = fmaxf(fmaxf(redm[0], redm[1]), fmaxf(redm[2], redm[3]));

  float s = 0.f;
#pragma unroll
  for (int i = 0; i < 16; ++i) s += __expf(v[i] - m);
#pragma unroll
  for (int o = 32; o > 0; o >>= 1) s += __shfl_xor(s, o);
  if ((tid & 63) == 0) reds[wave] = s;
  __syncthreads();
  s = (reds[0] + reds[1]) + (reds[2] + reds[3]);

  if (tid == 0) minv[blockIdx.x] = make_float2(m, 1.0f / s);
}

extern "C" void kernel_launch(void* const* d_in, const int* in_sizes, int n_in,
                              void* d_out, int out_size, void* d_ws, size_t ws_size,
                              hipStream_t stream) {
  const float* x  = (const float*)d_in[0];   // (2,4096,1024) fp32, batch-major
  const float* Wq = (const float*)d_in[1];   // (1024,1024) fp32 (out,in)
  const float* Wk = (const float*)d_in[2];
  const float* Wv = (const float*)d_in[3];
  const float* Wo = (const float*)d_in[4];
  float* out = (float*)d_out;                // (2,4096,1024) FP32

  // ws layout (u16 units) — 136 MiB total
  u16* xb  = (u16*)d_ws;                     // 8192x1024 (dead after Vt)
  u16* Wqb = xb  + 8388608;                  // 1024x1024
  u16* Wkb = Wqb + 1048576;                  // contiguous after Wqb
  u16* Wvb = Wkb + 1048576;
  u16* Wob = Wvb + 1048576;
  u16* QKp = Wob + 1048576;                  // 8192x2048: Q cols 0-1023, Kp 1024+
  u16* Vt  = QKp + 16777216;                 // 1024x8192 (Vt[e][b*4096+l])
  u16* S   = Vt  + 8388608;                  // 2 x 4096x4096
  u16* O   = QKp;                            // alias: QKp dead after scores GEMM
  float2* minv = (float2*)xb;                // 8192 x (m, 1/s) — xb dead by then

  const dim3 blk(256);

  // 0: casts (x + all four W in one launch)
  cast_f32_bf16<<<dim3(4096), blk, 0, stream>>>(x, xb, 8388608);
  cast_w4_bf16<<<dim3(2048), blk, 0, stream>>>(Wq, Wk, Wv, Wo, Wqb);

  // 1: QKp = x @ [Wq;Wk]^T   (M=8192, N=2048, K=1024), 1024 blocks, XCD-swz
  gemm_bt<1><<<dim3(16, 64, 1), blk, 0, stream>>>(xb, Wqb, QKp,
                                                  1024, 1024, 1024, 2048,
                                                  0, 0, 0, 1.f, 0);
  // 2: Vt = Wv@x^T   (M=1024, N=8192, K=1024) -> ldc=8192, 512 blocks, natural
  gemm_bt<0><<<dim3(64, 8, 1), blk, 0, stream>>>(Wvb, xb, Vt,
                                                 1024, 1024, 1024, 8192,
                                                 0, 0, 0, 1.f, 0);
  // 3: S_z = Q_z @ Kp_z^T / 32  (M=N=4096, K=1024), z=2 — 256^2 fine-phase
  gemm256_8ph<<<dim3(16, 16, 2), dim3(512), 0, stream>>>(
      QKp, QKp + 1024, S, 1024, 2048, 2048, 4096,
      8388608LL, 8388608LL, 16777216LL, 0.03125f);
  // 4: row stats (replaces full softmax: no S write-back)
  rowstat_rows<<<dim3(8192), blk, 0, stream>>>(S, minv);
  // 5: O_z = softmax(S_z) @ V_z fused: exp on af-fragments + 1/s epilogue
  pv_bt<<<dim3(8, 32, 2), blk, 0, stream>>>(S, Vt, O, minv,
                                            4096, 4096, 8192, 1024,
                                            16777216LL, 4096LL, 4194304LL);
  // 6: out = O @ Wo^T   (M=8192, N=1024, K=1024), FP32 store, XCD-swz
  gemm_bt<1><<<dim3(8, 64, 1), blk, 0, stream>>>(O, Wob, out,
                                                 1024, 1024, 1024, 1024,
                                                 0, 0, 0, 1.f, 1);
}

// Round 13
// 385.881 us; speedup vs baseline: 1.2519x; 1.2519x over previous
//
#include <hip/hip_runtime.h>
#include <hip/hip_bf16.h>
#include <stdint.h>

// MultiHeadedSelfAttention: B=2, L=4096, D=1024, H=1. fp32 inputs, FP32 output.
// Round 25: REVERT of round-24's softmax fusion (pv_bt 98->218µs: 32 exps vs
// 16 MFMA per thread per K-tile made PV VALU-bound, VALUBusy 60%/MfmaUtil 13%
// — in-loop softmax recompute is 8x-amplified by N-tiling; the 28µs BW-bound
// softmax pass is cheaper). Back to round-10 structure (389.8µs best), plus
// ONE grounded change: QKp switches to gemm256_8ph (K=1024 shape, grid
// (8,32)=256 blocks — round-10 proved this kernel beats 2-barrier gemm_bt on
// the identical-K scores shape, <98 vs 105µs). Vt/PV/final keep gemm_bt
// (their 256^2 grids would be 128 blocks = half the GPU idle).
// Pipeline:
//   0. cast x (grid 4096); cast W4 (grid 2048)
//   1. QKp = x @ [Wq;Wk]^T    (8192x2048, K=1024)  grid 256   [gemm256_8ph]
//   2. Vt  = Wv @ x^T          (1024x8192)          grid 512   [gemm_bt<0>]
//   3. S_z = Q_z @ Kp_z^T/32   (2x 4096x4096)       grid 512   [gemm256_8ph]
//   4. softmax rows (8192 rows)
//   5. O_z = P_z @ V_z         -> O into QKp region grid 512   [gemm_bt<1>]
//   6. out = O @ Wo^T -> FP32 d_out                 grid 512   [gemm_bt<1>]
// ws (u16): xb 8.39M | W*b 4x1.05M | QKp 16.78M | Vt 8.39M | S 33.55M
// = 71,303,168 u16 = 136 MiB (layout proven safe in prior rounds).

typedef unsigned short u16;
typedef short short8 __attribute__((ext_vector_type(8)));
typedef float f32x4 __attribute__((ext_vector_type(4)));

__device__ __forceinline__ void async_ld16(void* lds, const void* g) {
  __builtin_amdgcn_global_load_lds(
      (const __attribute__((address_space(1))) unsigned int*)g,
      (__attribute__((address_space(3))) unsigned int*)lds,
      16, 0, 0);
}

__device__ __forceinline__ u16 f2bf(float f) {  // RNE
  unsigned u = __float_as_uint(f);
  u += 0x7FFFu + ((u >> 16) & 1u);
  return (u16)(u >> 16);
}

// fp32 -> bf16, 8 elems/thread. n must be a multiple of 8 (true here).
__global__ __launch_bounds__(256)
void cast_f32_bf16(const float* __restrict__ in, u16* __restrict__ out, int n) {
  const int i = (blockIdx.x * 256 + threadIdx.x) * 8;
  if (i >= n) return;
  float4 a = ((const float4*)(in + i))[0];
  float4 b = ((const float4*)(in + i))[1];
  uint4 o;
  o.x = (unsigned)f2bf(a.x) | ((unsigned)f2bf(a.y) << 16);
  o.y = (unsigned)f2bf(a.z) | ((unsigned)f2bf(a.w) << 16);
  o.z = (unsigned)f2bf(b.x) | ((unsigned)f2bf(b.y) << 16);
  o.w = (unsigned)f2bf(b.z) | ((unsigned)f2bf(b.w) << 16);
  *(uint4*)(out + i) = o;
}

// 4 weight matrices (each n = 1<<20 fp32) -> one contiguous bf16 region.
__global__ __launch_bounds__(256)
void cast_w4_bf16(const float* __restrict__ w0, const float* __restrict__ w1,
                  const float* __restrict__ w2, const float* __restrict__ w3,
                  u16* __restrict__ out) {
  const int idx = (blockIdx.x * 256 + threadIdx.x) * 8;
  const int which = idx >> 20;
  const int off = idx & 1048575;
  const float* src = which == 0 ? w0 : which == 1 ? w1 : which == 2 ? w2 : w3;
  float4 a = ((const float4*)(src + off))[0];
  float4 b = ((const float4*)(src + off))[1];
  uint4 o;
  o.x = (unsigned)f2bf(a.x) | ((unsigned)f2bf(a.y) << 16);
  o.y = (unsigned)f2bf(a.z) | ((unsigned)f2bf(a.w) << 16);
  o.z = (unsigned)f2bf(b.x) | ((unsigned)f2bf(b.y) << 16);
  o.w = (unsigned)f2bf(b.z) | ((unsigned)f2bf(b.w) << 16);
  *(uint4*)(out + idx) = o;
}

#define BM 128
#define BN 128
#define BK 32

// ---- 128^2 workhorse: triple-buffered, depth-3, counted vmcnt(8/4/0).
template <int XSWZ>
__global__ __launch_bounds__(256)
void gemm_bt(const u16* __restrict__ A, const u16* __restrict__ Bt,
             void* __restrict__ Cv, int K, int lda, int ldb, int ldc,
             long long sAz, long long sBz, long long sCz,
             float scale, int store_f32) {
  __shared__ u16 As[3][BM * BK];
  __shared__ u16 Bs[3][BN * BK];

  int bx, by, bz;
  if constexpr (XSWZ) {
    const int gx = gridDim.x, gy = gridDim.y;
    const int nwg = gx * gy * gridDim.z;
    const int lin = (blockIdx.z * gy + blockIdx.y) * gx + blockIdx.x;
    const int chunk = nwg >> 3;
    const int swz = (lin & 7) * chunk + (lin >> 3);
    bx = swz % gx;
    const int t1 = swz / gx;
    by = t1 % gy;
    bz = t1 / gy;
  } else {
    bx = blockIdx.x; by = blockIdx.y; bz = blockIdx.z;
  }

  A  += (long long)bz * sAz;
  Bt += (long long)bz * sBz;

  const int tid  = threadIdx.x;
  const int wave = tid >> 6;
  const int lane = tid & 63;
  const int wm   = wave >> 1;
  const int wn   = wave & 1;
  const int r15  = lane & 15;
  const int q4   = lane >> 4;

  const int tileM = by * BM;
  const int tileN = bx * BN;

  const int srow = tid >> 2;
  const int scol = ((tid & 3) ^ (srow & 3)) * 8;

  const u16* Aptr = A + (long long)tileM * lda + scol;
  const u16* Bptr = Bt + (long long)tileN * ldb + scol;

  auto stage = [&](int kt) {
    const int b = kt % 3;
    const int k0 = kt * BK;
    u16* as = &As[b][tid * 8];
    u16* bs = &Bs[b][tid * 8];
    async_ld16(as,        Aptr + (long long)srow * lda + k0);
    async_ld16(as + 2048, Aptr + (long long)(srow + 64) * lda + k0);
    async_ld16(bs,        Bptr + (long long)srow * ldb + k0);
    async_ld16(bs + 2048, Bptr + (long long)(srow + 64) * ldb + k0);
  };

  f32x4 zero = {0.f, 0.f, 0.f, 0.f};
  f32x4 acc[4][4];
#pragma unroll
  for (int i = 0; i < 4; ++i)
#pragma unroll
    for (int j = 0; j < 4; ++j) acc[i][j] = zero;

  const int csw = ((q4 ^ (r15 & 3)) * 8);

  const int NT = K / BK;
  stage(0);
  if (NT > 1) stage(1);
  if (NT > 2) stage(2);

  for (int kt = 0; kt < NT; ++kt) {
    const int rem = NT - 1 - kt;
    if (rem >= 2)      asm volatile("s_waitcnt vmcnt(8)" ::: "memory");
    else if (rem == 1) asm volatile("s_waitcnt vmcnt(4)" ::: "memory");
    else               asm volatile("s_waitcnt vmcnt(0)" ::: "memory");
    __builtin_amdgcn_s_barrier();

    const int b = kt % 3;
    const u16* as = &As[b][0];
    const u16* bs = &Bs[b][0];

    short8 af[4], bf[4];
#pragma unroll
    for (int i = 0; i < 4; ++i)
      af[i] = *(const short8*)&as[(wm * 64 + i * 16 + r15) * BK + csw];
#pragma unroll
    for (int i = 0; i < 4; ++i)
      bf[i] = *(const short8*)&bs[(wn * 64 + i * 16 + r15) * BK + csw];

    __builtin_amdgcn_s_setprio(1);
#pragma unroll
    for (int i = 0; i < 4; ++i)
#pragma unroll
      for (int j = 0; j < 4; ++j)
        acc[i][j] = __builtin_amdgcn_mfma_f32_16x16x32_bf16(af[i], bf[j], acc[i][j], 0, 0, 0);
    __builtin_amdgcn_s_setprio(0);

    __builtin_amdgcn_s_barrier();
    if (kt + 3 < NT) stage(kt + 3);
  }

#pragma unroll
  for (int i = 0; i < 4; ++i) {
#pragma unroll
    for (int j = 0; j < 4; ++j) {
      const int col = tileN + wn * 64 + j * 16 + r15;
#pragma unroll
      for (int r = 0; r < 4; ++r) {
        const int row = tileM + wm * 64 + i * 16 + q4 * 4 + r;
        const long long idx = (long long)bz * sCz + (long long)row * ldc + col;
        const float val = acc[i][j][r] * scale;
        if (store_f32) ((float*)Cv)[idx] = val;
        else           ((u16*)Cv)[idx] = f2bf(val);
      }
    }
  }
}

// ---------------------------------------------------------------------------
// 256x256 fine-phase GEMM: BK=32, 3 rotating buffers (96 KiB), 8 waves
// (2Mx4N), wave tile 128x64, acc[8][4]. Per K-tile t:
//   vmcnt(4)[last:0]; barrier;
//   ph0: ds_read bf[4]+af[4]; stage A(t+2); barrier; setprio 16 MFMA; barrier;
//   ph1: ds_read af[4](+64);  stage B(t+2); barrier; setprio 16 MFMA; barrier;
// Race-free (verified): tile τ staged during τ-2 into buf[τ%3], freed by
// τ-1's reads one barrier earlier; vmcnt(4) retires exactly tile t's 4 loads.
// Used for scores AND QKp (any shape with dims %256==0, K%32==0, nwg%8==0).
// ---------------------------------------------------------------------------
__global__ __launch_bounds__(512, 2)
void gemm256_8ph(const u16* __restrict__ A, const u16* __restrict__ Bt,
                 u16* __restrict__ C, int K, int lda, int ldb, int ldc,
                 long long sAz, long long sBz, long long sCz, float scale) {
  __shared__ u16 smem[49152];  // 3 x (A 256x32 + B 256x32) u16 = 96 KiB

  const int gx = gridDim.x, gy = gridDim.y;
  const int nwg = gx * gy * gridDim.z;
  const int lin = (blockIdx.z * gy + blockIdx.y) * gx + blockIdx.x;
  const int chunk = nwg >> 3;
  const int swz = (lin & 7) * chunk + (lin >> 3);
  const int bx = swz % gx;
  const int t1 = swz / gx;
  const int by = t1 % gy;
  const int bz = t1 / gy;

  A  += (long long)bz * sAz;
  Bt += (long long)bz * sBz;
  const long long cbase = (long long)bz * sCz;

  const int tid  = threadIdx.x;
  const int wid  = tid >> 6;
  const int lane = tid & 63;
  const int wm   = wid >> 2;
  const int wn   = wid & 3;
  const int r15  = lane & 15;
  const int q4   = lane >> 4;

  const int tileM = by * 256;
  const int tileN = bx * 256;

  const int sr  = tid >> 2;
  const int gc8 = ((((tid & 3) - ((tid >> 3) & 3)) & 3)) * 8;

  const u16* Asrc = A  + (long long)(tileM + sr) * lda + gc8;
  const u16* Bsrc = Bt + (long long)(tileN + sr) * ldb + gc8;

  auto stage2A = [&](int kt) {
    u16* d = &smem[(kt % 3) * 16384 + tid * 8];
    async_ld16(d,        Asrc + kt * 32);
    async_ld16(d + 4096, Asrc + (long long)128 * lda + kt * 32);
  };
  auto stage2B = [&](int kt) {
    u16* d = &smem[(kt % 3) * 16384 + 8192 + tid * 8];
    async_ld16(d,        Bsrc + kt * 32);
    async_ld16(d + 4096, Bsrc + (long long)128 * ldb + kt * 32);
  };

  const int csw = (((q4 + (r15 >> 1)) & 3)) * 8;

  f32x4 acc[8][4];
#pragma unroll
  for (int i = 0; i < 8; ++i)
#pragma unroll
    for (int j = 0; j < 4; ++j) acc[i][j] = (f32x4){0.f, 0.f, 0.f, 0.f};

  const int NT = K >> 5;

  stage2A(0); stage2B(0);
  if (NT > 1) { stage2A(1); stage2B(1); }

  for (int t = 0; t < NT; ++t) {
    if (t + 1 < NT) asm volatile("s_waitcnt vmcnt(4)" ::: "memory");
    else            asm volatile("s_waitcnt vmcnt(0)" ::: "memory");
    __builtin_amdgcn_s_barrier();

    const u16* bufA = &smem[(t % 3) * 16384];
    const u16* bufB = bufA + 8192;

    short8 bf[4], af[4];
#pragma unroll
    for (int j = 0; j < 4; ++j)
      bf[j] = *(const short8*)&bufB[(wn * 64 + j * 16 + r15) * 32 + csw];
#pragma unroll
    for (int i = 0; i < 4; ++i)
      af[i] = *(const short8*)&bufA[(wm * 128 + i * 16 + r15) * 32 + csw];
    if (t + 2 < NT) stage2A(t + 2);
    __builtin_amdgcn_s_barrier();

    __builtin_amdgcn_s_setprio(1);
#pragma unroll
    for (int i = 0; i < 4; ++i)
#pragma unroll
      for (int j = 0; j < 4; ++j)
        acc[i][j] = __builtin_amdgcn_mfma_f32_16x16x32_bf16(af[i], bf[j], acc[i][j], 0, 0, 0);
    __builtin_amdgcn_s_setprio(0);
    __builtin_amdgcn_s_barrier();

#pragma unroll
    for (int i = 0; i < 4; ++i)
      af[i] = *(const short8*)&bufA[(wm * 128 + 64 + i * 16 + r15) * 32 + csw];
    if (t + 2 < NT) stage2B(t + 2);
    __builtin_amdgcn_s_barrier();

    __builtin_amdgcn_s_setprio(1);
#pragma unroll
    for (int i = 0; i < 4; ++i)
#pragma unroll
      for (int j = 0; j < 4; ++j)
        acc[4 + i][j] = __builtin_amdgcn_mfma_f32_16x16x32_bf16(af[i], bf[j], acc[4 + i][j], 0, 0, 0);
    __builtin_amdgcn_s_setprio(0);
    __builtin_amdgcn_s_barrier();
  }

  const int crow = tileM + wm * 128 + q4 * 4;
  const int ccol = tileN + wn * 64 + r15;
#pragma unroll
  for (int mi = 0; mi < 8; ++mi)
#pragma unroll
    for (int nj = 0; nj < 4; ++nj)
#pragma unroll
      for (int r = 0; r < 4; ++r) {
        const long long row = crow + mi * 16 + r;
        C[cbase + row * ldc + (ccol + nj * 16)] = f2bf(acc[mi][nj][r] * scale);
      }
}

// In-place row softmax over 4096 bf16 columns. grid = rows, block = 256.
__global__ __launch_bounds__(256)
void softmax_rows(u16* __restrict__ S) {
  const int tid = threadIdx.x;
  u16* rp = S + (long long)blockIdx.x * 4096;

  uint4 a = ((const uint4*)rp)[tid * 2];
  uint4 b = ((const uint4*)rp)[tid * 2 + 1];
  unsigned w[8] = {a.x, a.y, a.z, a.w, b.x, b.y, b.z, b.w};
  float v[16];
#pragma unroll
  for (int i = 0; i < 8; ++i) {
    v[2 * i]     = __uint_as_float(w[i] << 16);
    v[2 * i + 1] = __uint_as_float(w[i] & 0xFFFF0000u);
  }

  float m = v[0];
#pragma unroll
  for (int i = 1; i < 16; ++i) m = fmaxf(m, v[i]);
#pragma unroll
  for (int o = 32; o > 0; o >>= 1) m = fmaxf(m, __shfl_xor(m, o));
  __shared__ float redm[4];
  __shared__ float reds[4];
  const int wave = tid >> 6;
  if ((tid & 63) == 0) redm[wave] = m;
  __syncthreads();
  m = fmaxf(fmaxf(redm[0], redm[1]), fmaxf(redm[2], redm[3]));

  float s = 0.f;
#pragma unroll
  for (int i = 0; i < 16; ++i) {
    v[i] = __expf(v[i] - m);
    s += v[i];
  }
#pragma unroll
  for (int o = 32; o > 0; o >>= 1) s += __shfl_xor(s, o);
  if ((tid & 63) == 0) reds[wave] = s;
  __syncthreads();
  s = (reds[0] + reds[1]) + (reds[2] + reds[3]);
  const float inv = 1.0f / s;

#pragma unroll
  for (int i = 0; i < 8; ++i)
    w[i] = (unsigned)f2bf(v[2 * i] * inv) | ((unsigned)f2bf(v[2 * i + 1] * inv) << 16);
  uint4 oa = {w[0], w[1], w[2], w[3]};
  uint4 ob = {w[4], w[5], w[6], w[7]};
  ((uint4*)rp)[tid * 2] = oa;
  ((uint4*)rp)[tid * 2 + 1] = ob;
}

extern "C" void kernel_launch(void* const* d_in, const int* in_sizes, int n_in,
                              void* d_out, int out_size, void* d_ws, size_t ws_size,
                              hipStream_t stream) {
  const float* x  = (const float*)d_in[0];   // (2,4096,1024) fp32, batch-major
  const float* Wq = (const float*)d_in[1];   // (1024,1024) fp32 (out,in)
  const float* Wk = (const float*)d_in[2];
  const float* Wv = (const float*)d_in[3];
  const float* Wo = (const float*)d_in[4];
  float* out = (float*)d_out;                // (2,4096,1024) FP32

  // ws layout (u16 units) — 136 MiB total
  u16* xb  = (u16*)d_ws;                     // 8192x1024
  u16* Wqb = xb  + 8388608;                  // 1024x1024
  u16* Wkb = Wqb + 1048576;                  // contiguous after Wqb
  u16* Wvb = Wkb + 1048576;
  u16* Wob = Wvb + 1048576;
  u16* QKp = Wob + 1048576;                  // 8192x2048: Q cols 0-1023, Kp 1024+
  u16* Vt  = QKp + 16777216;                 // 1024x8192 (Vt[e][b*4096+l])
  u16* S   = Vt  + 8388608;                  // 2 x 4096x4096
  u16* O   = QKp;                            // alias: QKp dead after scores GEMM

  const dim3 blk(256);

  // 0: casts (x + all four W in one launch)
  cast_f32_bf16<<<dim3(4096), blk, 0, stream>>>(x, xb, 8388608);
  cast_w4_bf16<<<dim3(2048), blk, 0, stream>>>(Wq, Wk, Wv, Wo, Wqb);

  // 1: QKp = x @ [Wq;Wk]^T   (M=8192, N=2048, K=1024) — 256^2 fine-phase,
  //    grid (8,32,1) = 256 blocks x 512 threads.
  gemm256_8ph<<<dim3(8, 32, 1), dim3(512), 0, stream>>>(
      xb, Wqb, QKp, 1024, 1024, 1024, 2048,
      0, 0, 0, 1.f);
  // 2: Vt = Wv@x^T   (M=1024, N=8192, K=1024) -> ldc=8192, 512 blocks, natural
  gemm_bt<0><<<dim3(64, 8, 1), blk, 0, stream>>>(Wvb, xb, Vt,
                                                 1024, 1024, 1024, 8192,
                                                 0, 0, 0, 1.f, 0);
  // 3: S_z = Q_z @ Kp_z^T / 32  (M=N=4096, K=1024), z=2 — 256^2 fine-phase
  gemm256_8ph<<<dim3(16, 16, 2), dim3(512), 0, stream>>>(
      QKp, QKp + 1024, S, 1024, 2048, 2048, 4096,
      8388608LL, 8388608LL, 16777216LL, 0.03125f);
  // 4: softmax in place, 8192 rows
  softmax_rows<<<dim3(8192), blk, 0, stream>>>(S);
  // 5: O_z = P_z @ V_z == BT(A=S_z, Bt=Vt+z*4096, ldb=8192) -> O, XCD-swz
  gemm_bt<1><<<dim3(8, 32, 2), blk, 0, stream>>>(S, Vt, O,
                                                 4096, 4096, 8192, 1024,
                                                 16777216LL, 4096LL, 4194304LL,
                                                 1.f, 0);
  // 6: out = O @ Wo^T   (M=8192, N=1024, K=1024), FP32 store, XCD-swz
  gemm_bt<1><<<dim3(8, 64, 1), blk, 0, stream>>>(O, Wob, out,
                                                 1024, 1024, 1024, 1024,
                                                 0, 0, 0, 1.f, 1);
}

// Round 14
// 367.530 us; speedup vs baseline: 1.3144x; 1.0499x over previous
//
#include <hip/hip_runtime.h>
#include <hip/hip_bf16.h>
#include <stdint.h>

// MultiHeadedSelfAttention: B=2, L=4096, D=1024, H=1. fp32 inputs, FP32 output.
// Round 26: PV moves to the fine-phase schedule via a BN=128 variant of the
// proven 256^2 kernel (gemm256f<128>): block tile 256x128, 8 waves, wave tile
// 128x32 (NF=2), 3 rotating 24KB buffers (72KiB LDS), 3 loads/tile, counted
// vmcnt(3). Grid (8,16,2)=256 blocks = 1/CU, 8 waves/CU — same wave count as
// the 2-barrier PV but with the schedule that won on scores (<=98 vs 104-108)
// and QKp. Scores/QKp keep gemm256f<256> (bit-identical to round-13).
// Round-13 evidence: PV top-5 at 107.7us (MfmaUtil 26%, HBM 9.7% — structure
// bound); cross-round noise +-10% so only within-round signatures compared.
// Pipeline:
//   0. cast x (grid 4096); cast W4 (grid 2048)
//   1. QKp = x @ [Wq;Wk]^T    (8192x2048, K=1024)  grid 256   [gemm256f<256>]
//   2. Vt  = Wv @ x^T          (1024x8192)          grid 512   [gemm_bt<0>]
//   3. S_z = Q_z @ Kp_z^T/32   (2x 4096x4096)       grid 512   [gemm256f<256>]
//   4. softmax rows (8192 rows)
//   5. O_z = P_z @ V_z         -> O into QKp region grid 256   [gemm256f<128>]
//   6. out = O @ Wo^T -> FP32 d_out                 grid 512   [gemm_bt<1>]
// ws (u16): xb 8.39M | W*b 4x1.05M | QKp 16.78M | Vt 8.39M | S 33.55M
// = 71,303,168 u16 = 136 MiB (layout proven safe in prior rounds).

typedef unsigned short u16;
typedef short short8 __attribute__((ext_vector_type(8)));
typedef float f32x4 __attribute__((ext_vector_type(4)));

__device__ __forceinline__ void async_ld16(void* lds, const void* g) {
  __builtin_amdgcn_global_load_lds(
      (const __attribute__((address_space(1))) unsigned int*)g,
      (__attribute__((address_space(3))) unsigned int*)lds,
      16, 0, 0);
}

__device__ __forceinline__ u16 f2bf(float f) {  // RNE
  unsigned u = __float_as_uint(f);
  u += 0x7FFFu + ((u >> 16) & 1u);
  return (u16)(u >> 16);
}

// fp32 -> bf16, 8 elems/thread. n must be a multiple of 8 (true here).
__global__ __launch_bounds__(256)
void cast_f32_bf16(const float* __restrict__ in, u16* __restrict__ out, int n) {
  const int i = (blockIdx.x * 256 + threadIdx.x) * 8;
  if (i >= n) return;
  float4 a = ((const float4*)(in + i))[0];
  float4 b = ((const float4*)(in + i))[1];
  uint4 o;
  o.x = (unsigned)f2bf(a.x) | ((unsigned)f2bf(a.y) << 16);
  o.y = (unsigned)f2bf(a.z) | ((unsigned)f2bf(a.w) << 16);
  o.z = (unsigned)f2bf(b.x) | ((unsigned)f2bf(b.y) << 16);
  o.w = (unsigned)f2bf(b.z) | ((unsigned)f2bf(b.w) << 16);
  *(uint4*)(out + i) = o;
}

// 4 weight matrices (each n = 1<<20 fp32) -> one contiguous bf16 region.
__global__ __launch_bounds__(256)
void cast_w4_bf16(const float* __restrict__ w0, const float* __restrict__ w1,
                  const float* __restrict__ w2, const float* __restrict__ w3,
                  u16* __restrict__ out) {
  const int idx = (blockIdx.x * 256 + threadIdx.x) * 8;
  const int which = idx >> 20;
  const int off = idx & 1048575;
  const float* src = which == 0 ? w0 : which == 1 ? w1 : which == 2 ? w2 : w3;
  float4 a = ((const float4*)(src + off))[0];
  float4 b = ((const float4*)(src + off))[1];
  uint4 o;
  o.x = (unsigned)f2bf(a.x) | ((unsigned)f2bf(a.y) << 16);
  o.y = (unsigned)f2bf(a.z) | ((unsigned)f2bf(a.w) << 16);
  o.z = (unsigned)f2bf(b.x) | ((unsigned)f2bf(b.y) << 16);
  o.w = (unsigned)f2bf(b.z) | ((unsigned)f2bf(b.w) << 16);
  *(uint4*)(out + idx) = o;
}

#define BM 128
#define BN 128
#define BK 32

// ---- 128^2 workhorse: triple-buffered, depth-3, counted vmcnt(8/4/0).
template <int XSWZ>
__global__ __launch_bounds__(256)
void gemm_bt(const u16* __restrict__ A, const u16* __restrict__ Bt,
             void* __restrict__ Cv, int K, int lda, int ldb, int ldc,
             long long sAz, long long sBz, long long sCz,
             float scale, int store_f32) {
  __shared__ u16 As[3][BM * BK];
  __shared__ u16 Bs[3][BN * BK];

  int bx, by, bz;
  if constexpr (XSWZ) {
    const int gx = gridDim.x, gy = gridDim.y;
    const int nwg = gx * gy * gridDim.z;
    const int lin = (blockIdx.z * gy + blockIdx.y) * gx + blockIdx.x;
    const int chunk = nwg >> 3;
    const int swz = (lin & 7) * chunk + (lin >> 3);
    bx = swz % gx;
    const int t1 = swz / gx;
    by = t1 % gy;
    bz = t1 / gy;
  } else {
    bx = blockIdx.x; by = blockIdx.y; bz = blockIdx.z;
  }

  A  += (long long)bz * sAz;
  Bt += (long long)bz * sBz;

  const int tid  = threadIdx.x;
  const int wave = tid >> 6;
  const int lane = tid & 63;
  const int wm   = wave >> 1;
  const int wn   = wave & 1;
  const int r15  = lane & 15;
  const int q4   = lane >> 4;

  const int tileM = by * BM;
  const int tileN = bx * BN;

  const int srow = tid >> 2;
  const int scol = ((tid & 3) ^ (srow & 3)) * 8;

  const u16* Aptr = A + (long long)tileM * lda + scol;
  const u16* Bptr = Bt + (long long)tileN * ldb + scol;

  auto stage = [&](int kt) {
    const int b = kt % 3;
    const int k0 = kt * BK;
    u16* as = &As[b][tid * 8];
    u16* bs = &Bs[b][tid * 8];
    async_ld16(as,        Aptr + (long long)srow * lda + k0);
    async_ld16(as + 2048, Aptr + (long long)(srow + 64) * lda + k0);
    async_ld16(bs,        Bptr + (long long)srow * ldb + k0);
    async_ld16(bs + 2048, Bptr + (long long)(srow + 64) * ldb + k0);
  };

  f32x4 zero = {0.f, 0.f, 0.f, 0.f};
  f32x4 acc[4][4];
#pragma unroll
  for (int i = 0; i < 4; ++i)
#pragma unroll
    for (int j = 0; j < 4; ++j) acc[i][j] = zero;

  const int csw = ((q4 ^ (r15 & 3)) * 8);

  const int NT = K / BK;
  stage(0);
  if (NT > 1) stage(1);
  if (NT > 2) stage(2);

  for (int kt = 0; kt < NT; ++kt) {
    const int rem = NT - 1 - kt;
    if (rem >= 2)      asm volatile("s_waitcnt vmcnt(8)" ::: "memory");
    else if (rem == 1) asm volatile("s_waitcnt vmcnt(4)" ::: "memory");
    else               asm volatile("s_waitcnt vmcnt(0)" ::: "memory");
    __builtin_amdgcn_s_barrier();

    const int b = kt % 3;
    const u16* as = &As[b][0];
    const u16* bs = &Bs[b][0];

    short8 af[4], bf[4];
#pragma unroll
    for (int i = 0; i < 4; ++i)
      af[i] = *(const short8*)&as[(wm * 64 + i * 16 + r15) * BK + csw];
#pragma unroll
    for (int i = 0; i < 4; ++i)
      bf[i] = *(const short8*)&bs[(wn * 64 + i * 16 + r15) * BK + csw];

    __builtin_amdgcn_s_setprio(1);
#pragma unroll
    for (int i = 0; i < 4; ++i)
#pragma unroll
      for (int j = 0; j < 4; ++j)
        acc[i][j] = __builtin_amdgcn_mfma_f32_16x16x32_bf16(af[i], bf[j], acc[i][j], 0, 0, 0);
    __builtin_amdgcn_s_setprio(0);

    __builtin_amdgcn_s_barrier();
    if (kt + 3 < NT) stage(kt + 3);
  }

#pragma unroll
  for (int i = 0; i < 4; ++i) {
#pragma unroll
    for (int j = 0; j < 4; ++j) {
      const int col = tileN + wn * 64 + j * 16 + r15;
#pragma unroll
      for (int r = 0; r < 4; ++r) {
        const int row = tileM + wm * 64 + i * 16 + q4 * 4 + r;
        const long long idx = (long long)bz * sCz + (long long)row * ldc + col;
        const float val = acc[i][j][r] * scale;
        if (store_f32) ((float*)Cv)[idx] = val;
        else           ((u16*)Cv)[idx] = f2bf(val);
      }
    }
  }
}

// ---------------------------------------------------------------------------
// Fine-phase GEMM, block tile 256 x BNN (BNN = 256 or 128): BK=32, 3 rotating
// buffers, 8 waves (2M x 4N), wave tile 128 x BNN/4, NF = BNN/64 fragments.
// Loads/tile L = 2 + BNN/128 (A:2, B:BNN/128). Per K-tile t:
//   vmcnt(L)[last:0]; barrier;
//   ph0: ds_read bf[NF]+af[4]; stage A(t+2); barrier; setprio MFMA; barrier;
//   ph1: ds_read af[4](+64);   stage B(t+2); barrier; setprio MFMA; barrier;
// Race-free (proven at BNN=256 on scores/QKp): tile τ staged during τ-2 into
// buf[τ%3], freed by τ-1's reads one barrier earlier; vmcnt(L) retires
// exactly tile t's L loads. Bank permutation: LDS slot (row,c) holds global
// chunk (c-(row>>1))&3 via inverse-swizzled source; read c=(q4+(r15>>1))&3
// (per-lane constant: row bases are multiples of 16).
// ---------------------------------------------------------------------------
template <int BNN>
__global__ __launch_bounds__(512, 2)
void gemm256f(const u16* __restrict__ A, const u16* __restrict__ Bt,
              u16* __restrict__ C, int K, int lda, int ldb, int ldc,
              long long sAz, long long sBz, long long sCz, float scale) {
  constexpr int NF   = BNN / 64;          // B fragments per wave (4 or 2)
  constexpr int BUFU = 8192 + BNN * 32;   // u16 per buffer (A 256x32 + B BNNx32)
  __shared__ u16 smem[3 * BUFU];

  const int gx = gridDim.x, gy = gridDim.y;
  const int nwg = gx * gy * gridDim.z;
  const int lin = (blockIdx.z * gy + blockIdx.y) * gx + blockIdx.x;
  const int chunk = nwg >> 3;
  const int swz = (lin & 7) * chunk + (lin >> 3);
  const int bx = swz % gx;
  const int t1 = swz / gx;
  const int by = t1 % gy;
  const int bz = t1 / gy;

  A  += (long long)bz * sAz;
  Bt += (long long)bz * sBz;
  const long long cbase = (long long)bz * sCz;

  const int tid  = threadIdx.x;
  const int wid  = tid >> 6;
  const int lane = tid & 63;
  const int wm   = wid >> 2;       // 0..1 (M half, 128 rows)
  const int wn   = wid & 3;        // 0..3 (N quarter, BNN/4 cols)
  const int r15  = lane & 15;
  const int q4   = lane >> 4;

  const int tileM = by * 256;
  const int tileN = bx * BNN;

  // staging: thread -> (row = tid>>2 in 0..127, chunk slot = tid&3);
  // source col = inverse-permuted chunk ((tid&3) - (row>>1))&3.
  const int sr  = tid >> 2;
  const int gc8 = ((((tid & 3) - ((tid >> 3) & 3)) & 3)) * 8;

  const u16* Asrc = A  + (long long)(tileM + sr) * lda + gc8;
  const u16* Bsrc = Bt + (long long)(tileN + sr) * ldb + gc8;

  auto stage2A = [&](int kt) {
    u16* d = &smem[(kt % 3) * BUFU + tid * 8];
    async_ld16(d,        Asrc + kt * 32);
    async_ld16(d + 4096, Asrc + (long long)128 * lda + kt * 32);
  };
  auto stage2B = [&](int kt) {
    u16* d = &smem[(kt % 3) * BUFU + 8192 + tid * 8];
    async_ld16(d, Bsrc + kt * 32);
    if constexpr (BNN == 256)
      async_ld16(d + 4096, Bsrc + (long long)128 * ldb + kt * 32);
  };

  const int csw = (((q4 + (r15 >> 1)) & 3)) * 8;

  f32x4 acc[8][NF];
#pragma unroll
  for (int i = 0; i < 8; ++i)
#pragma unroll
    for (int j = 0; j < NF; ++j) acc[i][j] = (f32x4){0.f, 0.f, 0.f, 0.f};

  const int NT = K >> 5;   // BK = 32

  stage2A(0); stage2B(0);
  if (NT > 1) { stage2A(1); stage2B(1); }

  for (int t = 0; t < NT; ++t) {
    if (t + 1 < NT) {
      if constexpr (BNN == 256)
        asm volatile("s_waitcnt vmcnt(4)" ::: "memory");
      else
        asm volatile("s_waitcnt vmcnt(3)" ::: "memory");
    } else {
      asm volatile("s_waitcnt vmcnt(0)" ::: "memory");
    }
    __builtin_amdgcn_s_barrier();

    const u16* bufA = &smem[(t % 3) * BUFU];
    const u16* bufB = bufA + 8192;

    // ---- phase 0: B (whole wave quarter) + A rows 0-63 of this wave's half
    short8 bf[NF], af[4];
#pragma unroll
    for (int j = 0; j < NF; ++j)
      bf[j] = *(const short8*)&bufB[(wn * (BNN / 4) + j * 16 + r15) * 32 + csw];
#pragma unroll
    for (int i = 0; i < 4; ++i)
      af[i] = *(const short8*)&bufA[(wm * 128 + i * 16 + r15) * 32 + csw];
    if (t + 2 < NT) stage2A(t + 2);
    __builtin_amdgcn_s_barrier();

    __builtin_amdgcn_s_setprio(1);
#pragma unroll
    for (int i = 0; i < 4; ++i)
#pragma unroll
      for (int j = 0; j < NF; ++j)
        acc[i][j] = __builtin_amdgcn_mfma_f32_16x16x32_bf16(af[i], bf[j], acc[i][j], 0, 0, 0);
    __builtin_amdgcn_s_setprio(0);
    __builtin_amdgcn_s_barrier();

    // ---- phase 1: A rows 64-127
#pragma unroll
    for (int i = 0; i < 4; ++i)
      af[i] = *(const short8*)&bufA[(wm * 128 + 64 + i * 16 + r15) * 32 + csw];
    if (t + 2 < NT) stage2B(t + 2);
    __builtin_amdgcn_s_barrier();

    __builtin_amdgcn_s_setprio(1);
#pragma unroll
    for (int i = 0; i < 4; ++i)
#pragma unroll
      for (int j = 0; j < NF; ++j)
        acc[4 + i][j] = __builtin_amdgcn_mfma_f32_16x16x32_bf16(af[i], bf[j], acc[4 + i][j], 0, 0, 0);
    __builtin_amdgcn_s_setprio(0);
    __builtin_amdgcn_s_barrier();
  }

  // epilogue: col = lane&15, row = q4*4 + reg  [e2e-verified mapping]
  const int crow = tileM + wm * 128 + q4 * 4;
  const int ccol = tileN + wn * (BNN / 4) + r15;
#pragma unroll
  for (int mi = 0; mi < 8; ++mi)
#pragma unroll
    for (int nj = 0; nj < NF; ++nj)
#pragma unroll
      for (int r = 0; r < 4; ++r) {
        const long long row = crow + mi * 16 + r;
        C[cbase + row * ldc + (ccol + nj * 16)] = f2bf(acc[mi][nj][r] * scale);
      }
}

// In-place row softmax over 4096 bf16 columns. grid = rows, block = 256.
__global__ __launch_bounds__(256)
void softmax_rows(u16* __restrict__ S) {
  const int tid = threadIdx.x;
  u16* rp = S + (long long)blockIdx.x * 4096;

  uint4 a = ((const uint4*)rp)[tid * 2];
  uint4 b = ((const uint4*)rp)[tid * 2 + 1];
  unsigned w[8] = {a.x, a.y, a.z, a.w, b.x, b.y, b.z, b.w};
  float v[16];
#pragma unroll
  for (int i = 0; i < 8; ++i) {
    v[2 * i]     = __uint_as_float(w[i] << 16);
    v[2 * i + 1] = __uint_as_float(w[i] & 0xFFFF0000u);
  }

  float m = v[0];
#pragma unroll
  for (int i = 1; i < 16; ++i) m = fmaxf(m, v[i]);
#pragma unroll
  for (int o = 32; o > 0; o >>= 1) m = fmaxf(m, __shfl_xor(m, o));
  __shared__ float redm[4];
  __shared__ float reds[4];
  const int wave = tid >> 6;
  if ((tid & 63) == 0) redm[wave] = m;
  __syncthreads();
  m = fmaxf(fmaxf(redm[0], redm[1]), fmaxf(redm[2], redm[3]));

  float s = 0.f;
#pragma unroll
  for (int i = 0; i < 16; ++i) {
    v[i] = __expf(v[i] - m);
    s += v[i];
  }
#pragma unroll
  for (int o = 32; o > 0; o >>= 1) s += __shfl_xor(s, o);
  if ((tid & 63) == 0) reds[wave] = s;
  __syncthreads();
  s = (reds[0] + reds[1]) + (reds[2] + reds[3]);
  const float inv = 1.0f / s;

#pragma unroll
  for (int i = 0; i < 8; ++i)
    w[i] = (unsigned)f2bf(v[2 * i] * inv) | ((unsigned)f2bf(v[2 * i + 1] * inv) << 16);
  uint4 oa = {w[0], w[1], w[2], w[3]};
  uint4 ob = {w[4], w[5], w[6], w[7]};
  ((uint4*)rp)[tid * 2] = oa;
  ((uint4*)rp)[tid * 2 + 1] = ob;
}

extern "C" void kernel_launch(void* const* d_in, const int* in_sizes, int n_in,
                              void* d_out, int out_size, void* d_ws, size_t ws_size,
                              hipStream_t stream) {
  const float* x  = (const float*)d_in[0];   // (2,4096,1024) fp32, batch-major
  const float* Wq = (const float*)d_in[1];   // (1024,1024) fp32 (out,in)
  const float* Wk = (const float*)d_in[2];
  const float* Wv = (const float*)d_in[3];
  const float* Wo = (const float*)d_in[4];
  float* out = (float*)d_out;                // (2,4096,1024) FP32

  // ws layout (u16 units) — 136 MiB total
  u16* xb  = (u16*)d_ws;                     // 8192x1024
  u16* Wqb = xb  + 8388608;                  // 1024x1024
  u16* Wkb = Wqb + 1048576;                  // contiguous after Wqb
  u16* Wvb = Wkb + 1048576;
  u16* Wob = Wvb + 1048576;
  u16* QKp = Wob + 1048576;                  // 8192x2048: Q cols 0-1023, Kp 1024+
  u16* Vt  = QKp + 16777216;                 // 1024x8192 (Vt[e][b*4096+l])
  u16* S   = Vt  + 8388608;                  // 2 x 4096x4096
  u16* O   = QKp;                            // alias: QKp dead after scores GEMM

  const dim3 blk(256);

  // 0: casts (x + all four W in one launch)
  cast_f32_bf16<<<dim3(4096), blk, 0, stream>>>(x, xb, 8388608);
  cast_w4_bf16<<<dim3(2048), blk, 0, stream>>>(Wq, Wk, Wv, Wo, Wqb);

  // 1: QKp = x @ [Wq;Wk]^T   (M=8192, N=2048, K=1024) — fine-phase 256^2,
  //    grid (8,32,1) = 256 blocks x 512 threads.
  gemm256f<256><<<dim3(8, 32, 1), dim3(512), 0, stream>>>(
      xb, Wqb, QKp, 1024, 1024, 1024, 2048,
      0, 0, 0, 1.f);
  // 2: Vt = Wv@x^T   (M=1024, N=8192, K=1024) -> ldc=8192, 512 blocks, natural
  gemm_bt<0><<<dim3(64, 8, 1), blk, 0, stream>>>(Wvb, xb, Vt,
                                                 1024, 1024, 1024, 8192,
                                                 0, 0, 0, 1.f, 0);
  // 3: S_z = Q_z @ Kp_z^T / 32  (M=N=4096, K=1024), z=2 — fine-phase 256^2
  gemm256f<256><<<dim3(16, 16, 2), dim3(512), 0, stream>>>(
      QKp, QKp + 1024, S, 1024, 2048, 2048, 4096,
      8388608LL, 8388608LL, 16777216LL, 0.03125f);
  // 4: softmax in place, 8192 rows
  softmax_rows<<<dim3(8192), blk, 0, stream>>>(S);
  // 5: O_z = P_z @ V_z == BT(A=S_z, Bt=Vt+z*4096, ldb=8192) -> O.
  //    Fine-phase 256x128: grid (8,16,2) = 256 blocks x 512 threads, 1/CU.
  gemm256f<128><<<dim3(8, 16, 2), dim3(512), 0, stream>>>(
      S, Vt, O, 4096, 4096, 8192, 1024,
      16777216LL, 4096LL, 4194304LL, 1.f);
  // 6: out = O @ Wo^T   (M=8192, N=1024, K=1024), FP32 store, XCD-swz
  gemm_bt<1><<<dim3(8, 64, 1), blk, 0, stream>>>(O, Wob, out,
                                                 1024, 1024, 1024, 1024,
                                                 0, 0, 0, 1.f, 1);
}

// Round 15
// 349.976 us; speedup vs baseline: 1.3803x; 1.0502x over previous
//
#include <hip/hip_runtime.h>
#include <hip/hip_bf16.h>
#include <stdint.h>

// MultiHeadedSelfAttention: B=2, L=4096, D=1024, H=1. fp32 inputs, FP32 output.
// Round 27: ALL GEMMs on the fine-phase schedule. Round-14 evidence:
// gemm256f measures SQ_LDS_BANK_CONFLICT = 0 vs gemm_bt's (real) 8.4M, and
// PV on gemm256f<128> went 107.7 -> 89.2us. Vt and final get gemm256f<128>
// geometries (grid 256 = 1/CU each; swizzle keeps same-panel blocks on one
// XCD for both shapes); final uses a new STF32 store flag (store-only
// change). gemm_bt retired.
// Pipeline:
//   0. cast x (grid 4096); cast W4 (grid 2048)
//   1. QKp = x @ [Wq;Wk]^T    (8192x2048, K=1024)  grid 256  [gemm256f<256>]
//   2. Vt  = Wv @ x^T          (1024x8192)          grid 256  [gemm256f<128>]
//   3. S_z = Q_z @ Kp_z^T/32   (2x 4096x4096)       grid 512  [gemm256f<256>]
//   4. softmax rows (8192 rows)
//   5. O_z = P_z @ V_z         -> O into QKp region grid 256  [gemm256f<128>]
//   6. out = O @ Wo^T -> FP32 d_out                 grid 256  [gemm256f<128,STF32>]
// ws (u16): xb 8.39M | W*b 4x1.05M | QKp 16.78M | Vt 8.39M | S 33.55M
// = 71,303,168 u16 = 136 MiB (layout proven safe in prior rounds).

typedef unsigned short u16;
typedef short short8 __attribute__((ext_vector_type(8)));
typedef float f32x4 __attribute__((ext_vector_type(4)));

__device__ __forceinline__ void async_ld16(void* lds, const void* g) {
  __builtin_amdgcn_global_load_lds(
      (const __attribute__((address_space(1))) unsigned int*)g,
      (__attribute__((address_space(3))) unsigned int*)lds,
      16, 0, 0);
}

__device__ __forceinline__ u16 f2bf(float f) {  // RNE
  unsigned u = __float_as_uint(f);
  u += 0x7FFFu + ((u >> 16) & 1u);
  return (u16)(u >> 16);
}

// fp32 -> bf16, 8 elems/thread. n must be a multiple of 8 (true here).
__global__ __launch_bounds__(256)
void cast_f32_bf16(const float* __restrict__ in, u16* __restrict__ out, int n) {
  const int i = (blockIdx.x * 256 + threadIdx.x) * 8;
  if (i >= n) return;
  float4 a = ((const float4*)(in + i))[0];
  float4 b = ((const float4*)(in + i))[1];
  uint4 o;
  o.x = (unsigned)f2bf(a.x) | ((unsigned)f2bf(a.y) << 16);
  o.y = (unsigned)f2bf(a.z) | ((unsigned)f2bf(a.w) << 16);
  o.z = (unsigned)f2bf(b.x) | ((unsigned)f2bf(b.y) << 16);
  o.w = (unsigned)f2bf(b.z) | ((unsigned)f2bf(b.w) << 16);
  *(uint4*)(out + i) = o;
}

// 4 weight matrices (each n = 1<<20 fp32) -> one contiguous bf16 region.
__global__ __launch_bounds__(256)
void cast_w4_bf16(const float* __restrict__ w0, const float* __restrict__ w1,
                  const float* __restrict__ w2, const float* __restrict__ w3,
                  u16* __restrict__ out) {
  const int idx = (blockIdx.x * 256 + threadIdx.x) * 8;
  const int which = idx >> 20;
  const int off = idx & 1048575;
  const float* src = which == 0 ? w0 : which == 1 ? w1 : which == 2 ? w2 : w3;
  float4 a = ((const float4*)(src + off))[0];
  float4 b = ((const float4*)(src + off))[1];
  uint4 o;
  o.x = (unsigned)f2bf(a.x) | ((unsigned)f2bf(a.y) << 16);
  o.y = (unsigned)f2bf(a.z) | ((unsigned)f2bf(a.w) << 16);
  o.z = (unsigned)f2bf(b.x) | ((unsigned)f2bf(b.y) << 16);
  o.w = (unsigned)f2bf(b.z) | ((unsigned)f2bf(b.w) << 16);
  *(uint4*)(out + idx) = o;
}

// ---------------------------------------------------------------------------
// Fine-phase GEMM, block tile 256 x BNN (BNN = 256 or 128): BK=32, 3 rotating
// buffers, 8 waves (2M x 4N), wave tile 128 x BNN/4, NF = BNN/64 fragments.
// Loads/tile L = 2 + BNN/128. Per K-tile t:
//   vmcnt(L)[last:0]; barrier;
//   ph0: ds_read bf[NF]+af[4]; stage A(t+2); barrier; setprio MFMA; barrier;
//   ph1: ds_read af[4](+64);   stage B(t+2); barrier; setprio MFMA; barrier;
// Race-free (proven on scores/QKp/PV): tile τ staged during τ-2 into
// buf[τ%3], freed by τ-1's reads one barrier earlier; vmcnt(L) retires
// exactly tile t's L loads. Bank permutation (measured conflict-free): LDS
// slot (row,c) holds global chunk (c-(row>>1))&3 via inverse-swizzled
// source; read c=(q4+(r15>>1))&3. STF32=1 stores fp32 (final GEMM).
// ---------------------------------------------------------------------------
template <int BNN, int STF32>
__global__ __launch_bounds__(512, 2)
void gemm256f(const u16* __restrict__ A, const u16* __restrict__ Bt,
              void* __restrict__ Cv, int K, int lda, int ldb, int ldc,
              long long sAz, long long sBz, long long sCz, float scale) {
  constexpr int NF   = BNN / 64;          // B fragments per wave (4 or 2)
  constexpr int BUFU = 8192 + BNN * 32;   // u16 per buffer (A 256x32 + B BNNx32)
  __shared__ u16 smem[3 * BUFU];

  const int gx = gridDim.x, gy = gridDim.y;
  const int nwg = gx * gy * gridDim.z;
  const int lin = (blockIdx.z * gy + blockIdx.y) * gx + blockIdx.x;
  const int chunk = nwg >> 3;
  const int swz = (lin & 7) * chunk + (lin >> 3);
  const int bx = swz % gx;
  const int t1 = swz / gx;
  const int by = t1 % gy;
  const int bz = t1 / gy;

  A  += (long long)bz * sAz;
  Bt += (long long)bz * sBz;
  const long long cbase = (long long)bz * sCz;

  const int tid  = threadIdx.x;
  const int wid  = tid >> 6;
  const int lane = tid & 63;
  const int wm   = wid >> 2;       // 0..1 (M half, 128 rows)
  const int wn   = wid & 3;        // 0..3 (N quarter, BNN/4 cols)
  const int r15  = lane & 15;
  const int q4   = lane >> 4;

  const int tileM = by * 256;
  const int tileN = bx * BNN;

  // staging: thread -> (row = tid>>2 in 0..127, chunk slot = tid&3);
  // source col = inverse-permuted chunk ((tid&3) - (row>>1))&3.
  const int sr  = tid >> 2;
  const int gc8 = ((((tid & 3) - ((tid >> 3) & 3)) & 3)) * 8;

  const u16* Asrc = A  + (long long)(tileM + sr) * lda + gc8;
  const u16* Bsrc = Bt + (long long)(tileN + sr) * ldb + gc8;

  auto stage2A = [&](int kt) {
    u16* d = &smem[(kt % 3) * BUFU + tid * 8];
    async_ld16(d,        Asrc + kt * 32);
    async_ld16(d + 4096, Asrc + (long long)128 * lda + kt * 32);
  };
  auto stage2B = [&](int kt) {
    u16* d = &smem[(kt % 3) * BUFU + 8192 + tid * 8];
    async_ld16(d, Bsrc + kt * 32);
    if constexpr (BNN == 256)
      async_ld16(d + 4096, Bsrc + (long long)128 * ldb + kt * 32);
  };

  const int csw = (((q4 + (r15 >> 1)) & 3)) * 8;

  f32x4 acc[8][NF];
#pragma unroll
  for (int i = 0; i < 8; ++i)
#pragma unroll
    for (int j = 0; j < NF; ++j) acc[i][j] = (f32x4){0.f, 0.f, 0.f, 0.f};

  const int NT = K >> 5;   // BK = 32

  stage2A(0); stage2B(0);
  if (NT > 1) { stage2A(1); stage2B(1); }

  for (int t = 0; t < NT; ++t) {
    if (t + 1 < NT) {
      if constexpr (BNN == 256)
        asm volatile("s_waitcnt vmcnt(4)" ::: "memory");
      else
        asm volatile("s_waitcnt vmcnt(3)" ::: "memory");
    } else {
      asm volatile("s_waitcnt vmcnt(0)" ::: "memory");
    }
    __builtin_amdgcn_s_barrier();

    const u16* bufA = &smem[(t % 3) * BUFU];
    const u16* bufB = bufA + 8192;

    // ---- phase 0: B (whole wave quarter) + A rows 0-63 of this wave's half
    short8 bf[NF], af[4];
#pragma unroll
    for (int j = 0; j < NF; ++j)
      bf[j] = *(const short8*)&bufB[(wn * (BNN / 4) + j * 16 + r15) * 32 + csw];
#pragma unroll
    for (int i = 0; i < 4; ++i)
      af[i] = *(const short8*)&bufA[(wm * 128 + i * 16 + r15) * 32 + csw];
    if (t + 2 < NT) stage2A(t + 2);
    __builtin_amdgcn_s_barrier();

    __builtin_amdgcn_s_setprio(1);
#pragma unroll
    for (int i = 0; i < 4; ++i)
#pragma unroll
      for (int j = 0; j < NF; ++j)
        acc[i][j] = __builtin_amdgcn_mfma_f32_16x16x32_bf16(af[i], bf[j], acc[i][j], 0, 0, 0);
    __builtin_amdgcn_s_setprio(0);
    __builtin_amdgcn_s_barrier();

    // ---- phase 1: A rows 64-127
#pragma unroll
    for (int i = 0; i < 4; ++i)
      af[i] = *(const short8*)&bufA[(wm * 128 + 64 + i * 16 + r15) * 32 + csw];
    if (t + 2 < NT) stage2B(t + 2);
    __builtin_amdgcn_s_barrier();

    __builtin_amdgcn_s_setprio(1);
#pragma unroll
    for (int i = 0; i < 4; ++i)
#pragma unroll
      for (int j = 0; j < NF; ++j)
        acc[4 + i][j] = __builtin_amdgcn_mfma_f32_16x16x32_bf16(af[i], bf[j], acc[4 + i][j], 0, 0, 0);
    __builtin_amdgcn_s_setprio(0);
    __builtin_amdgcn_s_barrier();
  }

  // epilogue: col = lane&15, row = q4*4 + reg  [e2e-verified mapping]
  const int crow = tileM + wm * 128 + q4 * 4;
  const int ccol = tileN + wn * (BNN / 4) + r15;
#pragma unroll
  for (int mi = 0; mi < 8; ++mi)
#pragma unroll
    for (int nj = 0; nj < NF; ++nj)
#pragma unroll
      for (int r = 0; r < 4; ++r) {
        const long long row = crow + mi * 16 + r;
        const long long idx = cbase + row * ldc + (ccol + nj * 16);
        const float val = acc[mi][nj][r] * scale;
        if constexpr (STF32) ((float*)Cv)[idx] = val;
        else                 ((u16*)Cv)[idx] = f2bf(val);
      }
}

// In-place row softmax over 4096 bf16 columns. grid = rows, block = 256.
__global__ __launch_bounds__(256)
void softmax_rows(u16* __restrict__ S) {
  const int tid = threadIdx.x;
  u16* rp = S + (long long)blockIdx.x * 4096;

  uint4 a = ((const uint4*)rp)[tid * 2];
  uint4 b = ((const uint4*)rp)[tid * 2 + 1];
  unsigned w[8] = {a.x, a.y, a.z, a.w, b.x, b.y, b.z, b.w};
  float v[16];
#pragma unroll
  for (int i = 0; i < 8; ++i) {
    v[2 * i]     = __uint_as_float(w[i] << 16);
    v[2 * i + 1] = __uint_as_float(w[i] & 0xFFFF0000u);
  }

  float m = v[0];
#pragma unroll
  for (int i = 1; i < 16; ++i) m = fmaxf(m, v[i]);
#pragma unroll
  for (int o = 32; o > 0; o >>= 1) m = fmaxf(m, __shfl_xor(m, o));
  __shared__ float redm[4];
  __shared__ float reds[4];
  const int wave = tid >> 6;
  if ((tid & 63) == 0) redm[wave] = m;
  __syncthreads();
  m = fmaxf(fmaxf(redm[0], redm[1]), fmaxf(redm[2], redm[3]));

  float s = 0.f;
#pragma unroll
  for (int i = 0; i < 16; ++i) {
    v[i] = __expf(v[i] - m);
    s += v[i];
  }
#pragma unroll
  for (int o = 32; o > 0; o >>= 1) s += __shfl_xor(s, o);
  if ((tid & 63) == 0) reds[wave] = s;
  __syncthreads();
  s = (reds[0] + reds[1]) + (reds[2] + reds[3]);
  const float inv = 1.0f / s;

#pragma unroll
  for (int i = 0; i < 8; ++i)
    w[i] = (unsigned)f2bf(v[2 * i] * inv) | ((unsigned)f2bf(v[2 * i + 1] * inv) << 16);
  uint4 oa = {w[0], w[1], w[2], w[3]};
  uint4 ob = {w[4], w[5], w[6], w[7]};
  ((uint4*)rp)[tid * 2] = oa;
  ((uint4*)rp)[tid * 2 + 1] = ob;
}

extern "C" void kernel_launch(void* const* d_in, const int* in_sizes, int n_in,
                              void* d_out, int out_size, void* d_ws, size_t ws_size,
                              hipStream_t stream) {
  const float* x  = (const float*)d_in[0];   // (2,4096,1024) fp32, batch-major
  const float* Wq = (const float*)d_in[1];   // (1024,1024) fp32 (out,in)
  const float* Wk = (const float*)d_in[2];
  const float* Wv = (const float*)d_in[3];
  const float* Wo = (const float*)d_in[4];
  float* out = (float*)d_out;                // (2,4096,1024) FP32

  // ws layout (u16 units) — 136 MiB total
  u16* xb  = (u16*)d_ws;                     // 8192x1024
  u16* Wqb = xb  + 8388608;                  // 1024x1024
  u16* Wkb = Wqb + 1048576;                  // contiguous after Wqb
  u16* Wvb = Wkb + 1048576;
  u16* Wob = Wvb + 1048576;
  u16* QKp = Wob + 1048576;                  // 8192x2048: Q cols 0-1023, Kp 1024+
  u16* Vt  = QKp + 16777216;                 // 1024x8192 (Vt[e][b*4096+l])
  u16* S   = Vt  + 8388608;                  // 2 x 4096x4096
  u16* O   = QKp;                            // alias: QKp dead after scores GEMM

  const dim3 blk(256);
  const dim3 blk512(512);

  // 0: casts (x + all four W in one launch)
  cast_f32_bf16<<<dim3(4096), blk, 0, stream>>>(x, xb, 8388608);
  cast_w4_bf16<<<dim3(2048), blk, 0, stream>>>(Wq, Wk, Wv, Wo, Wqb);

  // 1: QKp = x @ [Wq;Wk]^T   (M=8192, N=2048, K=1024) — fine-phase 256^2,
  //    grid (8,32,1) = 256 blocks.
  gemm256f<256, 0><<<dim3(8, 32, 1), blk512, 0, stream>>>(
      xb, Wqb, QKp, 1024, 1024, 1024, 2048,
      0, 0, 0, 1.f);
  // 2: Vt = Wv@x^T   (M=1024, N=8192, K=1024) -> ldc=8192 — fine-phase
  //    256x128, grid (64,4,1) = 256 blocks (same-B-panel blocks share XCD:
  //    64 % 8 == 0 under the bijective swizzle).
  gemm256f<128, 0><<<dim3(64, 4, 1), blk512, 0, stream>>>(
      Wvb, xb, Vt, 1024, 1024, 1024, 8192,
      0, 0, 0, 1.f);
  // 3: S_z = Q_z @ Kp_z^T / 32  (M=N=4096, K=1024), z=2 — fine-phase 256^2
  gemm256f<256, 0><<<dim3(16, 16, 2), blk512, 0, stream>>>(
      QKp, QKp + 1024, S, 1024, 2048, 2048, 4096,
      8388608LL, 8388608LL, 16777216LL, 0.03125f);
  // 4: softmax in place, 8192 rows
  softmax_rows<<<dim3(8192), blk, 0, stream>>>(S);
  // 5: O_z = P_z @ V_z == BT(A=S_z, Bt=Vt+z*4096, ldb=8192) -> O.
  //    Fine-phase 256x128: grid (8,16,2) = 256 blocks.
  gemm256f<128, 0><<<dim3(8, 16, 2), blk512, 0, stream>>>(
      S, Vt, O, 4096, 4096, 8192, 1024,
      16777216LL, 4096LL, 4194304LL, 1.f);
  // 6: out = O @ Wo^T   (M=8192, N=1024, K=1024), FP32 store — fine-phase
  //    256x128, grid (8,32,1) = 256 blocks.
  gemm256f<128, 1><<<dim3(8, 32, 1), blk512, 0, stream>>>(
      O, Wob, out, 1024, 1024, 1024, 1024,
      0, 0, 0, 1.f);
}